// Round 5
// baseline (267.127 us; speedup 1.0000x reference)
//
#include <hip/hip_runtime.h>
#include <math.h>

#define T_SEQ  1024
#define C_DIM  1024
#define NH_    16
#define H_DIM  64
#define SCL    (0.125f * 1.4426950408889634f)   // 1/sqrt(64) folded with log2e

typedef __bf16 bf16;
typedef __bf16 bf16x4 __attribute__((ext_vector_type(4)));
typedef __bf16 bf16x8 __attribute__((ext_vector_type(8)));
typedef float  f32x4  __attribute__((ext_vector_type(4)));

#define MFMA16(a, b, c) __builtin_amdgcn_mfma_f32_16x16x32_bf16(a, b, c, 0, 0, 0)

#define GLOAD_LDS16(g, l) __builtin_amdgcn_global_load_lds( \
    (const __attribute__((address_space(1))) void*)(g),     \
    (__attribute__((address_space(3))) void*)(l), 16, 0, 0)

__device__ __forceinline__ bf16x8 neg8(bf16x8 x) {
    union { bf16x8 v; unsigned int u[4]; } t;
    t.v = x;
    t.u[0] ^= 0x80008000u; t.u[1] ^= 0x80008000u;
    t.u[2] ^= 0x80008000u; t.u[3] ^= 0x80008000u;
    return t.v;
}

// fragment read from XOR-8-chunk-swizzled [rows][64] bf16 plane
__device__ __forceinline__ bf16x8 frag_sw(const bf16* plane, int row, int chunk) {
    int c = chunk ^ (row & 7);
    return *(const bf16x8*)&plane[row * 64 + c * 8];
}
// fragment read from XOR-4-chunk-swizzled [rows][32] bf16 plane
__device__ __forceinline__ bf16x8 frag_sw4(const bf16* plane, int row, int chunk) {
    int c = chunk ^ (row & 3);
    return *(const bf16x8*)&plane[row * 32 + c * 8];
}

// ---------------------------------------------------------------------------
// splits: fp32 complex [R][1024][2] -> bf16 planes (re, im). z picks source.
// z==5 builds the RoPE phasor table.
// ---------------------------------------------------------------------------
__global__ __launch_bounds__(256)
void split_all(const float* __restrict__ x,  const float* __restrict__ wq,
               const float* __restrict__ wk, const float* __restrict__ wv,
               const float* __restrict__ wo,
               bf16* Xr, bf16* Xi, bf16* Wqr, bf16* Wqi, bf16* Wkr, bf16* Wki,
               bf16* Wvr, bf16* Wvi, bf16* Wor, bf16* Woi,
               float* __restrict__ rope)
{
    int z = blockIdx.y;
    if (z == 5) {
        if (blockIdx.x >= 256) return;
        int idx = blockIdx.x * 256 + threadIdx.x;   // 65536
        int tp = idx >> 6, d = idx & 63;
        float invf = exp2f((float)d * -0.2076205059304601f);
        float fr = (float)tp * invf;
        float sn, cs; sincosf(fr, &sn, &cs);
        *(float2*)&rope[(size_t)idx * 2] = make_float2(cs, sn);
        return;
    }
    if (z > 0 && blockIdx.x >= 1024) return;
    const float* in; bf16 *pr, *pi;
    if      (z == 0) { in = x;  pr = Xr;  pi = Xi;  }
    else if (z == 1) { in = wq; pr = Wqr; pi = Wqi; }
    else if (z == 2) { in = wk; pr = Wkr; pi = Wki; }
    else if (z == 3) { in = wv; pr = Wvr; pi = Wvi; }
    else             { in = wo; pr = Wor; pi = Woi; }
    int idx = (blockIdx.x * 256 + threadIdx.x) * 4;
    float4 v0 = *(const float4*)(in + (size_t)idx * 2);
    float4 v1 = *(const float4*)(in + (size_t)idx * 2 + 4);
    bf16x4 r, im;
    r[0] = (bf16)v0.x; r[1] = (bf16)v0.z; r[2] = (bf16)v1.x; r[3] = (bf16)v1.z;
    im[0] = (bf16)v0.y; im[1] = (bf16)v0.w; im[2] = (bf16)v1.y; im[3] = (bf16)v1.w;
    *(bf16x4*)(pr + idx) = r;
    *(bf16x4*)(pi + idx) = im;
}

// ---------------------------------------------------------------------------
// 128x64 complex GEMM core, BK=64 (half the barriers of BK=32).
// MODE 1: q/k planes [B,H,T,64] + RoPE.  MODE 2: v planes transposed [B,H,64,T].
// LDS 48 KB: Ar[0) Ai[8192) Br[16384) Bi[20480) elems, XOR-8 swizzled [rows][64].
// ---------------------------------------------------------------------------
template<int MODE>
__device__ __forceinline__ void cgemm128(
    const bf16* __restrict__ Ar, const bf16* __restrict__ Ai,
    const bf16* __restrict__ Br, const bf16* __restrict__ Bi,
    const float* __restrict__ bias, const float* __restrict__ rope,
    bf16* __restrict__ Yr, bf16* __restrict__ Yi, int m0, int n0)
{
    __shared__ __attribute__((aligned(16))) bf16 smem[24576];  // 48 KB
    const int t = threadIdx.x, lane = t & 63, wave = t >> 6;
    const int wm = (wave >> 1) * 64, wn = (wave & 1) * 32;
    const int lm = lane & 15, quad = lane >> 4;
    const int s_lr = lane >> 3, s_c = (lane & 7) ^ s_lr;   // 8-row unit staging

    f32x4 accr[4][2], acci[4][2];
#pragma unroll
    for (int i = 0; i < 4; i++)
#pragma unroll
        for (int j = 0; j < 2; j++) { accr[i][j] = (f32x4)0.f; acci[i][j] = (f32x4)0.f; }

    for (int k0 = 0; k0 < C_DIM; k0 += 64) {
#pragma unroll
        for (int j = 0; j < 12; j++) {
            int c = wave + 4 * j;          // 48 units of 8 rows x 64
            const bf16* src; bf16* dst;
            if (c < 16)      {             src = Ar + (size_t)(m0 + c * 8 + s_lr) * C_DIM + k0 + s_c * 8; dst = smem + c * 512; }
            else if (c < 32) { int u = c - 16; src = Ai + (size_t)(m0 + u * 8 + s_lr) * C_DIM + k0 + s_c * 8; dst = smem + 8192 + u * 512; }
            else if (c < 40) { int u = c - 32; src = Br + (size_t)(n0 + u * 8 + s_lr) * C_DIM + k0 + s_c * 8; dst = smem + 16384 + u * 512; }
            else             { int u = c - 40; src = Bi + (size_t)(n0 + u * 8 + s_lr) * C_DIM + k0 + s_c * 8; dst = smem + 20480 + u * 512; }
            GLOAD_LDS16(src, dst);
        }
        __syncthreads();

#pragma unroll
        for (int kh = 0; kh < 2; kh++) {
            bf16x8 ar[4], ai_[4], br_[2], bi_[2], bn_[2];
#pragma unroll
            for (int i = 0; i < 4; i++) {
                ar[i]  = frag_sw(smem,        wm + i * 16 + lm, kh * 4 + quad);
                ai_[i] = frag_sw(smem + 8192, wm + i * 16 + lm, kh * 4 + quad);
            }
#pragma unroll
            for (int j = 0; j < 2; j++) {
                br_[j] = frag_sw(smem + 16384, wn + j * 16 + lm, kh * 4 + quad);
                bi_[j] = frag_sw(smem + 20480, wn + j * 16 + lm, kh * 4 + quad);
                bn_[j] = neg8(bi_[j]);
            }
#pragma unroll
            for (int i = 0; i < 4; i++)
#pragma unroll
                for (int j = 0; j < 2; j++) {
                    accr[i][j] = MFMA16(ar[i],  br_[j], accr[i][j]);
                    accr[i][j] = MFMA16(ai_[i], bn_[j], accr[i][j]);
                    acci[i][j] = MFMA16(ar[i],  bi_[j], acci[i][j]);
                    acci[i][j] = MFMA16(ai_[i], br_[j], acci[i][j]);
                }
        }
        __syncthreads();
    }

    const int h = n0 >> 6, bb = m0 >> 10, tbase = m0 & (T_SEQ - 1);

    if (MODE == 1) {
        // bias + RoPE rotate in place (table lookup)
#pragma unroll
        for (int i = 0; i < 4; i++)
#pragma unroll
            for (int j = 0; j < 2; j++) {
                int d = wn + j * 16 + lm;
                float2 bv = *(const float2*)&bias[2 * (n0 + d)];
#pragma unroll
                for (int r = 0; r < 4; r++) {
                    int tpos = tbase + wm + i * 16 + quad * 4 + r;
                    float2 ph = *(const float2*)&rope[((size_t)tpos * H_DIM + d) * 2];
                    float yr = accr[i][j][r] + bv.x;
                    float yi = acci[i][j][r] + bv.y;
                    accr[i][j][r] = yr * ph.x - yi * ph.y;
                    acci[i][j][r] = yr * ph.y + yi * ph.x;
                }
            }
        // two-pass LDS transpose -> b128 stores, planes [B,H,T,64]
        bf16* dsts[2] = { Yr, Yi };
#pragma unroll
        for (int pass = 0; pass < 2; pass++) {
            __syncthreads();
#pragma unroll
            for (int i = 0; i < 4; i++)
#pragma unroll
                for (int j = 0; j < 2; j++)
#pragma unroll
                    for (int r = 0; r < 4; r++)
                        smem[(wm + i * 16 + quad * 4 + r) * 72 + wn + j * 16 + lm] =
                            (bf16)(pass ? acci[i][j][r] : accr[i][j][r]);
            __syncthreads();
            bf16* dst = dsts[pass] + ((size_t)(bb * NH_ + h) * T_SEQ + tbase) * H_DIM;
#pragma unroll
            for (int p = 0; p < 4; p++) {
                int ch = t + 256 * p;
                int row = ch >> 3, o = (ch & 7) * 8;
                *(bf16x8*)&dst[row * H_DIM + o] = *(const bf16x8*)&smem[row * 72 + o];
            }
        }
    } else {
        // V: two-pass LDS transpose to [d][t] -> b128 stores, planes [B,H,64,T]
        bf16* dsts[2] = { Yr, Yi };
#pragma unroll
        for (int pass = 0; pass < 2; pass++) {
            __syncthreads();
#pragma unroll
            for (int i = 0; i < 4; i++)
#pragma unroll
                for (int j = 0; j < 2; j++) {
                    int d = wn + j * 16 + lm;
                    float2 bv = *(const float2*)&bias[2 * (n0 + d)];
                    float bb2 = pass ? bv.y : bv.x;
                    bf16x4 pk;
#pragma unroll
                    for (int r = 0; r < 4; r++)
                        pk[r] = (bf16)((pass ? acci[i][j][r] : accr[i][j][r]) + bb2);
                    *(bf16x4*)&smem[d * 136 + wm + i * 16 + quad * 4] = pk;
                }
            __syncthreads();
            bf16* dst = dsts[pass] + ((size_t)(bb * NH_ + h) * H_DIM) * T_SEQ + tbase;
#pragma unroll
            for (int p = 0; p < 4; p++) {
                int ch = t + 256 * p;
                int row = ch >> 4, o = (ch & 15) * 8;
                *(bf16x8*)&dst[(size_t)row * T_SEQ + o] = *(const bf16x8*)&smem[row * 136 + o];
            }
        }
    }
}

__global__ __launch_bounds__(256, 3)
void qkv_gemm(const bf16* __restrict__ Xr, const bf16* __restrict__ Xi,
              const bf16* __restrict__ Wqr, const bf16* __restrict__ Wqi,
              const bf16* __restrict__ Wkr, const bf16* __restrict__ Wki,
              const bf16* __restrict__ Wvr, const bf16* __restrict__ Wvi,
              const float* __restrict__ bq, const float* __restrict__ bk,
              const float* __restrict__ bv, const float* __restrict__ rope,
              bf16* Qr, bf16* Qi, bf16* Kr, bf16* Ki, bf16* Vr, bf16* Vi)
{
    int m0 = blockIdx.y * 128, n0 = blockIdx.x * 64;
    if (blockIdx.z == 0)      cgemm128<1>(Xr, Xi, Wqr, Wqi, bq, rope, Qr, Qi, m0, n0);
    else if (blockIdx.z == 1) cgemm128<1>(Xr, Xi, Wkr, Wki, bk, rope, Kr, Ki, m0, n0);
    else                      cgemm128<2>(Xr, Xi, Wvr, Wvi, bv, nullptr, Vr, Vi, m0, n0);
}

// ---------------------------------------------------------------------------
// 64x64 complex GEMM, BK=64 (final projection, fp32 interleaved out). 512 blocks.
// LDS 32 KB: Ar[0) Ai[4096) Br[8192) Bi[12288) elems.
// ---------------------------------------------------------------------------
__global__ __launch_bounds__(256, 4)
void out_gemm(const bf16* __restrict__ Ar, const bf16* __restrict__ Ai,
              const bf16* __restrict__ Br, const bf16* __restrict__ Bi,
              const float* __restrict__ bias, float* __restrict__ Y)
{
    __shared__ __attribute__((aligned(16))) bf16 sm[16384];   // 32 KB
    const int t = threadIdx.x, lane = t & 63, wave = t >> 6;
    const int lm = lane & 15, quad = lane >> 4;
    const int s_lr = lane >> 3, s_c = (lane & 7) ^ s_lr;
    const int wm = (wave >> 1) * 32, wn = (wave & 1) * 32;
    const int m0 = blockIdx.y * 64, n0 = blockIdx.x * 64;

    f32x4 accr[2][2], acci[2][2];
#pragma unroll
    for (int i = 0; i < 2; i++)
#pragma unroll
        for (int j = 0; j < 2; j++) { accr[i][j] = (f32x4)0.f; acci[i][j] = (f32x4)0.f; }

    for (int k0 = 0; k0 < C_DIM; k0 += 64) {
#pragma unroll
        for (int j = 0; j < 8; j++) {
            int c = wave + 4 * j;          // 32 units of 8 rows x 64
            const bf16* src; bf16* dst;
            if (c < 8)       {             src = Ar + (size_t)(m0 + c * 8 + s_lr) * C_DIM + k0 + s_c * 8; dst = sm + c * 512; }
            else if (c < 16) { int u = c - 8;  src = Ai + (size_t)(m0 + u * 8 + s_lr) * C_DIM + k0 + s_c * 8; dst = sm + 4096 + u * 512; }
            else if (c < 24) { int u = c - 16; src = Br + (size_t)(n0 + u * 8 + s_lr) * C_DIM + k0 + s_c * 8; dst = sm + 8192 + u * 512; }
            else             { int u = c - 24; src = Bi + (size_t)(n0 + u * 8 + s_lr) * C_DIM + k0 + s_c * 8; dst = sm + 12288 + u * 512; }
            GLOAD_LDS16(src, dst);
        }
        __syncthreads();
#pragma unroll
        for (int kh = 0; kh < 2; kh++) {
            bf16x8 ar[2], ai_[2], br_[2], bi_[2], bn_[2];
#pragma unroll
            for (int i = 0; i < 2; i++) {
                ar[i]  = frag_sw(sm,        wm + i * 16 + lm, kh * 4 + quad);
                ai_[i] = frag_sw(sm + 4096, wm + i * 16 + lm, kh * 4 + quad);
            }
#pragma unroll
            for (int j = 0; j < 2; j++) {
                br_[j] = frag_sw(sm + 8192,  wn + j * 16 + lm, kh * 4 + quad);
                bi_[j] = frag_sw(sm + 12288, wn + j * 16 + lm, kh * 4 + quad);
                bn_[j] = neg8(bi_[j]);
            }
#pragma unroll
            for (int i = 0; i < 2; i++)
#pragma unroll
                for (int j = 0; j < 2; j++) {
                    accr[i][j] = MFMA16(ar[i],  br_[j], accr[i][j]);
                    accr[i][j] = MFMA16(ai_[i], bn_[j], accr[i][j]);
                    acci[i][j] = MFMA16(ar[i],  bi_[j], acci[i][j]);
                    acci[i][j] = MFMA16(ai_[i], br_[j], acci[i][j]);
                }
        }
        __syncthreads();
    }
#pragma unroll
    for (int i = 0; i < 2; i++)
#pragma unroll
        for (int j = 0; j < 2; j++) {
            int n = n0 + wn + j * 16 + lm;
            float2 bv = *(const float2*)&bias[2 * n];
#pragma unroll
            for (int r = 0; r < 4; r++) {
                int m = m0 + wm + i * 16 + quad * 4 + r;
                *(float2*)&Y[((size_t)m * C_DIM + n) * 2] =
                    make_float2(accr[i][j][r] + bv.x, acci[i][j][r] + bv.y);
            }
        }
}

// ---------------------------------------------------------------------------
// MFMA flash attention, S^T layout, 8 waves (2 s-halves x 4 q-groups).
// Q/K planes [B,H,T,64], V planes [B,H,64,T]. Out: ABr/ABi [B*T][1024].
// LDS 48 KB. Pl: padded stride-40 layout (20-bank rows -> conflict-free).
// ---------------------------------------------------------------------------
__global__ __launch_bounds__(512, 4)
void attn_mfma(const bf16* __restrict__ Qpr, const bf16* __restrict__ Qpi,
               const bf16* __restrict__ Kpr, const bf16* __restrict__ Kpi,
               const bf16* __restrict__ Vtr, const bf16* __restrict__ Vti,
               bf16* __restrict__ ABr, bf16* __restrict__ ABi)
{
    __shared__ __attribute__((aligned(16))) bf16 smem[24576];  // 48 KB
    const int t = threadIdx.x, lane = t & 63, w = t >> 6;
    const int qg = w & 3, sh = w >> 2;
    const int lm = lane & 15, quad = lane >> 4;
    const int q0 = blockIdx.x * 64;
    const int h = blockIdx.y, b = blockIdx.z;
    const size_t hb = (size_t)(b * NH_ + h) * T_SEQ * H_DIM;
    const int s_lr = lane >> 3, s_c = (lane & 7) ^ s_lr;        // 8-chunk swizzle
    const int lr4 = lane >> 2, sc4 = ((lane & 3) ^ (lr4 & 3)) * 8;  // 4-chunk swizzle

    // stage Q (64 rows x 64), 16 chunks over 8 waves
    {
        const bf16* gq = (sh == 0 ? Qpr : Qpi) + hb + (size_t)q0 * H_DIM;
        bf16* lq = smem + sh * 4096;
#pragma unroll
        for (int j = 0; j < 2; j++) {
            int cc = qg * 2 + j;
            GLOAD_LDS16(gq + (cc * 8 + s_lr) * H_DIM + s_c * 8, lq + cc * 512);
        }
    }
    __syncthreads();

    bf16x8 qfr[2], qfi[2], nqfr[2];
#pragma unroll
    for (int kh = 0; kh < 2; kh++) {
        qfr[kh]  = frag_sw(smem,        qg * 16 + lm, kh * 4 + quad);
        qfi[kh]  = frag_sw(smem + 4096, qg * 16 + lm, kh * 4 + quad);
        nqfr[kh] = neg8(qfr[kh]);
    }

    bf16* Ks_r = smem + 8192 + sh * 8192;
    bf16* Ks_i = Ks_r + 2048;
    bf16* Vs_r = Ks_r + 4096;
    bf16* Vs_i = Ks_r + 6144;
    bf16* Pl   = smem;                     // 128 rows x 40 (32 + 8 pad), aliases Q
    const int prow = sh * 64 + qg * 16 + lm;

    f32x4 Or[4], Oi[4];
#pragma unroll
    for (int nt = 0; nt < 4; nt++) { Or[nt] = (f32x4)0.f; Oi[nt] = (f32x4)0.f; }
    float mold = 0.f, lsum = 0.f;

    for (int it = 0; it < 16; it++) {
        const int s0 = it * 32 + sh * 512;
        __syncthreads();
        {   // wave (qg, sh) stages plane qg of its s-half: 4 chunks
            if (qg < 2) {
                const bf16* gsrc = (qg == 0 ? Kpr : Kpi) + hb + (size_t)s0 * H_DIM;
                bf16* ldst = (qg == 0) ? Ks_r : Ks_i;
#pragma unroll
                for (int cc = 0; cc < 4; cc++)
                    GLOAD_LDS16(gsrc + (cc * 8 + s_lr) * H_DIM + s_c * 8, ldst + cc * 512);
            } else {
                const bf16* gsrc = (qg == 2 ? Vtr : Vti) + hb + s0;
                bf16* ldst = (qg == 2) ? Vs_r : Vs_i;
#pragma unroll
                for (int cc = 0; cc < 4; cc++)
                    GLOAD_LDS16(gsrc + (size_t)(cc * 16 + lr4) * T_SEQ + sc4, ldst + cc * 512);
            }
        }
        __syncthreads();

        // S^T scores: A = K frags (m = s), B = Q frags (n = q)
        float sc[2][4];
#pragma unroll
        for (int ct = 0; ct < 2; ct++) {
            f32x4 sre = (f32x4)0.f, sim = (f32x4)0.f;
#pragma unroll
            for (int kh = 0; kh < 2; kh++) {
                bf16x8 kr = frag_sw(Ks_r, ct * 16 + lm, kh * 4 + quad);
                bf16x8 ki = frag_sw(Ks_i, ct * 16 + lm, kh * 4 + quad);
                sre = MFMA16(kr, qfr[kh],  sre);
                sre = MFMA16(ki, qfi[kh],  sre);
                sim = MFMA16(kr, qfi[kh],  sim);
                sim = MFMA16(ki, nqfr[kh], sim);
            }
#pragma unroll
            for (int r = 0; r < 4; r++)
                sc[ct][r] = sqrtf(sre[r] * sre[r] + sim[r] * sim[r]) * SCL;
        }

        // online softmax, state per lane (q = lm), reduce across quads
        float mx = sc[0][0];
#pragma unroll
        for (int ct = 0; ct < 2; ct++)
#pragma unroll
            for (int r = 0; r < 4; r++) mx = fmaxf(mx, sc[ct][r]);
        mx = fmaxf(mx, __shfl_xor(mx, 16));
        mx = fmaxf(mx, __shfl_xor(mx, 32));
        float mnew = fmaxf(mold, mx);
        float alpha = exp2f(mold - mnew);
        float ps = 0.f;
#pragma unroll
        for (int ct = 0; ct < 2; ct++) {
            bf16x4 pk;
#pragma unroll
            for (int r = 0; r < 4; r++) {
                float p = exp2f(sc[ct][r] - mnew);
                ps += p;
                pk[r] = (bf16)p;
            }
            *(bf16x4*)&Pl[prow * 40 + ct * 16 + quad * 4] = pk;
        }
        ps += __shfl_xor(ps, 16);
        ps += __shfl_xor(ps, 32);
        lsum = lsum * alpha + ps;
        mold = mnew;

        float aO[4];
#pragma unroll
        for (int r = 0; r < 4; r++)
            aO[r] = __shfl(alpha, (quad << 4) + quad * 4 + r, 64);
#pragma unroll
        for (int nt = 0; nt < 4; nt++)
#pragma unroll
            for (int r = 0; r < 4; r++) { Or[nt][r] *= aO[r]; Oi[nt][r] *= aO[r]; }

        // PV: A = P (m = q), B = V^T frags
        bf16x8 pf = *(const bf16x8*)&Pl[prow * 40 + quad * 8];
#pragma unroll
        for (int nt = 0; nt < 4; nt++) {
            Or[nt] = MFMA16(pf, frag_sw4(Vs_r, nt * 16 + lm, quad), Or[nt]);
            Oi[nt] = MFMA16(pf, frag_sw4(Vs_i, nt * 16 + lm, quad), Oi[nt]);
        }
    }

    // merge s-halves: sh1 -> LDS, sh0 combines and writes out
    float* Of = (float*)(smem + 8192);   // 32 KB staging region
    float* ml = (float*)smem;            // Pl region, dead
    __syncthreads();
    if (sh == 1) {
#pragma unroll
        for (int nt = 0; nt < 4; nt++)
#pragma unroll
            for (int r = 0; r < 4; r++) {
                Of[((qg * 2 + 0) * 16 + quad * 4 + r) * 64 + nt * 16 + lm] = Or[nt][r];
                Of[((qg * 2 + 1) * 16 + quad * 4 + r) * 64 + nt * 16 + lm] = Oi[nt][r];
            }
        if (quad == 0) *(float2*)&ml[(qg * 16 + lm) * 2] = make_float2(mold, lsum);
    }
    __syncthreads();
    if (sh == 0) {
        float2 m2 = *(const float2*)&ml[(qg * 16 + lm) * 2];
        float mn = fmaxf(mold, m2.x);
        float a1 = exp2f(mold - mn), a2 = exp2f(m2.x - mn);
        lsum = a1 * lsum + a2 * m2.y;
        float a1r[4], a2r[4], linv[4];
        float lv = 1.f / lsum;
#pragma unroll
        for (int r = 0; r < 4; r++) {
            int src = (quad << 4) + quad * 4 + r;
            a1r[r]  = __shfl(a1, src, 64);
            a2r[r]  = __shfl(a2, src, 64);
            linv[r] = __shfl(lv, src, 64);
        }
        size_t mbase = (size_t)(b * T_SEQ + q0 + qg * 16 + quad * 4) * C_DIM;
        int colb = h * H_DIM + lm;
#pragma unroll
        for (int nt = 0; nt < 4; nt++)
#pragma unroll
            for (int r = 0; r < 4; r++) {
                float orv = a1r[r] * Or[nt][r] +
                            a2r[r] * Of[((qg * 2 + 0) * 16 + quad * 4 + r) * 64 + nt * 16 + lm];
                float oiv = a1r[r] * Oi[nt][r] +
                            a2r[r] * Of[((qg * 2 + 1) * 16 + quad * 4 + r) * 64 + nt * 16 + lm];
                size_t o = mbase + (size_t)r * C_DIM + colb + nt * 16;
                ABr[o] = (bf16)(orv * linv[r]);
                ABi[o] = (bf16)(oiv * linv[r]);
            }
    }
}

// ---------------------------------------------------------------------------
extern "C" void kernel_launch(void* const* d_in, const int* in_sizes, int n_in,
                              void* d_out, int out_size, void* d_ws, size_t ws_size,
                              hipStream_t stream) {
    const float* x  = (const float*)d_in[0];
    const float* wq = (const float*)d_in[1];
    const float* bq = (const float*)d_in[2];
    const float* wk = (const float*)d_in[3];
    const float* bk = (const float*)d_in[4];
    const float* wv = (const float*)d_in[5];
    const float* bv = (const float*)d_in[6];
    const float* wo = (const float*)d_in[7];
    const float* bo = (const float*)d_in[8];

    float* rope = (float*)d_ws;                       // 131072 floats (512 KB)
    bf16* w = (bf16*)(rope + 131072);
    const size_t MSZ = (size_t)2048 * 1024;
    const size_t WSZ = (size_t)1024 * 1024;
    const size_t PSZ = (size_t)2 * NH_ * T_SEQ * H_DIM;

    bf16 *Xr = w, *Xi = Xr + MSZ;
    bf16 *Wqr = Xi + MSZ,  *Wqi = Wqr + WSZ;
    bf16 *Wkr = Wqi + WSZ, *Wki = Wkr + WSZ;
    bf16 *Wvr = Wki + WSZ, *Wvi = Wvr + WSZ;
    bf16 *Wor = Wvi + WSZ, *Woi = Wor + WSZ;
    bf16 *Qr = Woi + WSZ, *Qi = Qr + PSZ;
    bf16 *Kr = Qi + PSZ,  *Ki = Kr + PSZ;
    bf16 *Vr = Ki + PSZ,  *Vi = Vr + PSZ;
    bf16 *ABr = Vi + PSZ, *ABi = ABr + MSZ;

    split_all<<<dim3(2048, 6), 256, 0, stream>>>(x, wq, wk, wv, wo,
        Xr, Xi, Wqr, Wqi, Wkr, Wki, Wvr, Wvi, Wor, Woi, rope);

    qkv_gemm<<<dim3(16, 16, 3), 256, 0, stream>>>(
        Xr, Xi, Wqr, Wqi, Wkr, Wki, Wvr, Wvi, bq, bk, bv, rope,
        Qr, Qi, Kr, Ki, Vr, Vi);

    attn_mfma<<<dim3(16, 16, 2), 512, 0, stream>>>(
        Qr, Qi, Kr, Ki, Vr, Vi, ABr, ABi);

    out_gemm<<<dim3(16, 32), 256, 0, stream>>>(ABr, ABi, Wor, Woi, bo, (float*)d_out);
}

// Round 6
// 238.007 us; speedup vs baseline: 1.1224x; 1.1224x over previous
//
#include <hip/hip_runtime.h>
#include <math.h>

#define T_SEQ  1024
#define C_DIM  1024
#define NH_    16
#define H_DIM  64
#define SCL    (0.125f * 1.4426950408889634f)   // 1/sqrt(64) folded with log2e

typedef __bf16 bf16;
typedef __bf16 bf16x4 __attribute__((ext_vector_type(4)));
typedef __bf16 bf16x8 __attribute__((ext_vector_type(8)));
typedef float  f32x4  __attribute__((ext_vector_type(4)));

#define MFMA16(a, b, c) __builtin_amdgcn_mfma_f32_16x16x32_bf16(a, b, c, 0, 0, 0)

#define GLOAD_LDS16(g, l) __builtin_amdgcn_global_load_lds( \
    (const __attribute__((address_space(1))) void*)(g),     \
    (__attribute__((address_space(3))) void*)(l), 16, 0, 0)

__device__ __forceinline__ bf16x8 neg8(bf16x8 x) {
    union { bf16x8 v; unsigned int u[4]; } t;
    t.v = x;
    t.u[0] ^= 0x80008000u; t.u[1] ^= 0x80008000u;
    t.u[2] ^= 0x80008000u; t.u[3] ^= 0x80008000u;
    return t.v;
}

// fragment read from XOR-8-chunk-swizzled [rows][64] bf16 plane
__device__ __forceinline__ bf16x8 frag_sw(const bf16* plane, int row, int chunk) {
    int c = chunk ^ (row & 7);
    return *(const bf16x8*)&plane[row * 64 + c * 8];
}
// fragment read from XOR-4-chunk-swizzled [rows][32] bf16 plane
__device__ __forceinline__ bf16x8 frag_sw4(const bf16* plane, int row, int chunk) {
    int c = chunk ^ (row & 3);
    return *(const bf16x8*)&plane[row * 32 + c * 8];
}

// ---------------------------------------------------------------------------
// splits: fp32 complex [R][1024][2] -> bf16 planes (re, im). z picks source.
// z==5 builds the RoPE phasor table.
// ---------------------------------------------------------------------------
__global__ __launch_bounds__(256)
void split_all(const float* __restrict__ x,  const float* __restrict__ wq,
               const float* __restrict__ wk, const float* __restrict__ wv,
               const float* __restrict__ wo,
               bf16* Xr, bf16* Xi, bf16* Wqr, bf16* Wqi, bf16* Wkr, bf16* Wki,
               bf16* Wvr, bf16* Wvi, bf16* Wor, bf16* Woi,
               float* __restrict__ rope)
{
    int z = blockIdx.y;
    if (z == 5) {
        if (blockIdx.x >= 256) return;
        int idx = blockIdx.x * 256 + threadIdx.x;   // 65536
        int tp = idx >> 6, d = idx & 63;
        float invf = exp2f((float)d * -0.2076205059304601f);
        float fr = (float)tp * invf;
        float sn, cs; sincosf(fr, &sn, &cs);
        *(float2*)&rope[(size_t)idx * 2] = make_float2(cs, sn);
        return;
    }
    if (z > 0 && blockIdx.x >= 1024) return;
    const float* in; bf16 *pr, *pi;
    if      (z == 0) { in = x;  pr = Xr;  pi = Xi;  }
    else if (z == 1) { in = wq; pr = Wqr; pi = Wqi; }
    else if (z == 2) { in = wk; pr = Wkr; pi = Wki; }
    else if (z == 3) { in = wv; pr = Wvr; pi = Wvi; }
    else             { in = wo; pr = Wor; pi = Woi; }
    int idx = (blockIdx.x * 256 + threadIdx.x) * 4;
    float4 v0 = *(const float4*)(in + (size_t)idx * 2);
    float4 v1 = *(const float4*)(in + (size_t)idx * 2 + 4);
    bf16x4 r, im;
    r[0] = (bf16)v0.x; r[1] = (bf16)v0.z; r[2] = (bf16)v1.x; r[3] = (bf16)v1.z;
    im[0] = (bf16)v0.y; im[1] = (bf16)v0.w; im[2] = (bf16)v1.y; im[3] = (bf16)v1.w;
    *(bf16x4*)(pr + idx) = r;
    *(bf16x4*)(pi + idx) = im;
}

// ---------------------------------------------------------------------------
// 128x64 complex GEMM core, BK=64. smem passed in (ONE shared alloc per block
// — runtime `mode` avoids duplicate template instantiations each owning LDS).
// mode 1: q/k planes [B,H,T,64] + RoPE.  mode 2: v planes transposed [B,H,64,T].
// smem: 24576 bf16 (48 KB): Ar[0) Ai[8192) Br[16384) Bi[20480), XOR-8 swizzled.
// ---------------------------------------------------------------------------
__device__ __forceinline__ void cgemm128(
    bf16* __restrict__ smem,
    const bf16* __restrict__ Ar, const bf16* __restrict__ Ai,
    const bf16* __restrict__ Br, const bf16* __restrict__ Bi,
    const float* __restrict__ bias, const float* __restrict__ rope,
    bf16* __restrict__ Yr, bf16* __restrict__ Yi, int m0, int n0, int mode)
{
    const int t = threadIdx.x, lane = t & 63, wave = t >> 6;
    const int wm = (wave >> 1) * 64, wn = (wave & 1) * 32;
    const int lm = lane & 15, quad = lane >> 4;
    const int s_lr = lane >> 3, s_c = (lane & 7) ^ s_lr;   // 8-row unit staging

    f32x4 accr[4][2], acci[4][2];
#pragma unroll
    for (int i = 0; i < 4; i++)
#pragma unroll
        for (int j = 0; j < 2; j++) { accr[i][j] = (f32x4)0.f; acci[i][j] = (f32x4)0.f; }

    for (int k0 = 0; k0 < C_DIM; k0 += 64) {
#pragma unroll
        for (int j = 0; j < 12; j++) {
            int c = wave + 4 * j;          // 48 units of 8 rows x 64
            const bf16* src; bf16* dst;
            if (c < 16)      {             src = Ar + (size_t)(m0 + c * 8 + s_lr) * C_DIM + k0 + s_c * 8; dst = smem + c * 512; }
            else if (c < 32) { int u = c - 16; src = Ai + (size_t)(m0 + u * 8 + s_lr) * C_DIM + k0 + s_c * 8; dst = smem + 8192 + u * 512; }
            else if (c < 40) { int u = c - 32; src = Br + (size_t)(n0 + u * 8 + s_lr) * C_DIM + k0 + s_c * 8; dst = smem + 16384 + u * 512; }
            else             { int u = c - 40; src = Bi + (size_t)(n0 + u * 8 + s_lr) * C_DIM + k0 + s_c * 8; dst = smem + 20480 + u * 512; }
            GLOAD_LDS16(src, dst);
        }
        __syncthreads();

#pragma unroll
        for (int kh = 0; kh < 2; kh++) {
            bf16x8 ar[4], ai_[4], br_[2], bi_[2], bn_[2];
#pragma unroll
            for (int i = 0; i < 4; i++) {
                ar[i]  = frag_sw(smem,        wm + i * 16 + lm, kh * 4 + quad);
                ai_[i] = frag_sw(smem + 8192, wm + i * 16 + lm, kh * 4 + quad);
            }
#pragma unroll
            for (int j = 0; j < 2; j++) {
                br_[j] = frag_sw(smem + 16384, wn + j * 16 + lm, kh * 4 + quad);
                bi_[j] = frag_sw(smem + 20480, wn + j * 16 + lm, kh * 4 + quad);
                bn_[j] = neg8(bi_[j]);
            }
#pragma unroll
            for (int i = 0; i < 4; i++)
#pragma unroll
                for (int j = 0; j < 2; j++) {
                    accr[i][j] = MFMA16(ar[i],  br_[j], accr[i][j]);
                    accr[i][j] = MFMA16(ai_[i], bn_[j], accr[i][j]);
                    acci[i][j] = MFMA16(ar[i],  bi_[j], acci[i][j]);
                    acci[i][j] = MFMA16(ai_[i], br_[j], acci[i][j]);
                }
        }
        __syncthreads();
    }

    const int h = n0 >> 6, bb = m0 >> 10, tbase = m0 & (T_SEQ - 1);

    if (mode == 1) {
        // bias + RoPE rotate in place (table lookup)
#pragma unroll
        for (int i = 0; i < 4; i++)
#pragma unroll
            for (int j = 0; j < 2; j++) {
                int d = wn + j * 16 + lm;
                float2 bv = *(const float2*)&bias[2 * (n0 + d)];
#pragma unroll
                for (int r = 0; r < 4; r++) {
                    int tpos = tbase + wm + i * 16 + quad * 4 + r;
                    float2 ph = *(const float2*)&rope[((size_t)tpos * H_DIM + d) * 2];
                    float yr = accr[i][j][r] + bv.x;
                    float yi = acci[i][j][r] + bv.y;
                    accr[i][j][r] = yr * ph.x - yi * ph.y;
                    acci[i][j][r] = yr * ph.y + yi * ph.x;
                }
            }
        // two-pass LDS transpose -> b128 stores, planes [B,H,T,64]
        bf16* dsts[2] = { Yr, Yi };
#pragma unroll
        for (int pass = 0; pass < 2; pass++) {
            __syncthreads();
#pragma unroll
            for (int i = 0; i < 4; i++)
#pragma unroll
                for (int j = 0; j < 2; j++)
#pragma unroll
                    for (int r = 0; r < 4; r++)
                        smem[(wm + i * 16 + quad * 4 + r) * 72 + wn + j * 16 + lm] =
                            (bf16)(pass ? acci[i][j][r] : accr[i][j][r]);
            __syncthreads();
            bf16* dst = dsts[pass] + ((size_t)(bb * NH_ + h) * T_SEQ + tbase) * H_DIM;
#pragma unroll
            for (int p = 0; p < 4; p++) {
                int ch = t + 256 * p;
                int row = ch >> 3, o = (ch & 7) * 8;
                *(bf16x8*)&dst[row * H_DIM + o] = *(const bf16x8*)&smem[row * 72 + o];
            }
        }
    } else {
        // V: two-pass LDS transpose to [d][t] -> b128 stores, planes [B,H,64,T]
        bf16* dsts[2] = { Yr, Yi };
#pragma unroll
        for (int pass = 0; pass < 2; pass++) {
            __syncthreads();
#pragma unroll
            for (int i = 0; i < 4; i++)
#pragma unroll
                for (int j = 0; j < 2; j++) {
                    int d = wn + j * 16 + lm;
                    float2 bv = *(const float2*)&bias[2 * (n0 + d)];
                    float bb2 = pass ? bv.y : bv.x;
                    bf16x4 pk;
#pragma unroll
                    for (int r = 0; r < 4; r++)
                        pk[r] = (bf16)((pass ? acci[i][j][r] : accr[i][j][r]) + bb2);
                    *(bf16x4*)&smem[d * 136 + wm + i * 16 + quad * 4] = pk;
                }
            __syncthreads();
            bf16* dst = dsts[pass] + ((size_t)(bb * NH_ + h) * H_DIM) * T_SEQ + tbase;
#pragma unroll
            for (int p = 0; p < 4; p++) {
                int ch = t + 256 * p;
                int row = ch >> 4, o = (ch & 15) * 8;
                *(bf16x8*)&dst[(size_t)row * T_SEQ + o] = *(const bf16x8*)&smem[row * 136 + o];
            }
        }
    }
}

__global__ __launch_bounds__(256, 3)
void qkv_gemm(const bf16* __restrict__ Xr, const bf16* __restrict__ Xi,
              const bf16* __restrict__ Wqr, const bf16* __restrict__ Wqi,
              const bf16* __restrict__ Wkr, const bf16* __restrict__ Wki,
              const bf16* __restrict__ Wvr, const bf16* __restrict__ Wvi,
              const float* __restrict__ bq, const float* __restrict__ bk,
              const float* __restrict__ bv, const float* __restrict__ rope,
              bf16* Qr, bf16* Qi, bf16* Kr, bf16* Ki, bf16* Vr, bf16* Vi)
{
    __shared__ __attribute__((aligned(16))) bf16 smem[24576];  // ONE 48 KB alloc
    int m0 = blockIdx.y * 128, n0 = blockIdx.x * 64;
    const bf16 *Br, *Bi; const float* bias; bf16 *Yr, *Yi; int mode;
    if (blockIdx.z == 0)      { Br = Wqr; Bi = Wqi; bias = bq; Yr = Qr; Yi = Qi; mode = 1; }
    else if (blockIdx.z == 1) { Br = Wkr; Bi = Wki; bias = bk; Yr = Kr; Yi = Ki; mode = 1; }
    else                      { Br = Wvr; Bi = Wvi; bias = bv; Yr = Vr; Yi = Vi; mode = 2; }
    cgemm128(smem, Xr, Xi, Br, Bi, bias, rope, Yr, Yi, m0, n0, mode);
}

// ---------------------------------------------------------------------------
// 64x64 complex GEMM, BK=64 (final projection, fp32 interleaved out). 512 blocks.
// LDS 32 KB: Ar[0) Ai[4096) Br[8192) Bi[12288) elems.
// ---------------------------------------------------------------------------
__global__ __launch_bounds__(256, 4)
void out_gemm(const bf16* __restrict__ Ar, const bf16* __restrict__ Ai,
              const bf16* __restrict__ Br, const bf16* __restrict__ Bi,
              const float* __restrict__ bias, float* __restrict__ Y)
{
    __shared__ __attribute__((aligned(16))) bf16 sm[16384];   // 32 KB
    const int t = threadIdx.x, lane = t & 63, wave = t >> 6;
    const int lm = lane & 15, quad = lane >> 4;
    const int s_lr = lane >> 3, s_c = (lane & 7) ^ s_lr;
    const int wm = (wave >> 1) * 32, wn = (wave & 1) * 32;
    const int m0 = blockIdx.y * 64, n0 = blockIdx.x * 64;

    f32x4 accr[2][2], acci[2][2];
#pragma unroll
    for (int i = 0; i < 2; i++)
#pragma unroll
        for (int j = 0; j < 2; j++) { accr[i][j] = (f32x4)0.f; acci[i][j] = (f32x4)0.f; }

    for (int k0 = 0; k0 < C_DIM; k0 += 64) {
#pragma unroll
        for (int j = 0; j < 8; j++) {
            int c = wave + 4 * j;          // 32 units of 8 rows x 64
            const bf16* src; bf16* dst;
            if (c < 8)       {             src = Ar + (size_t)(m0 + c * 8 + s_lr) * C_DIM + k0 + s_c * 8; dst = sm + c * 512; }
            else if (c < 16) { int u = c - 8;  src = Ai + (size_t)(m0 + u * 8 + s_lr) * C_DIM + k0 + s_c * 8; dst = sm + 4096 + u * 512; }
            else if (c < 24) { int u = c - 16; src = Br + (size_t)(n0 + u * 8 + s_lr) * C_DIM + k0 + s_c * 8; dst = sm + 8192 + u * 512; }
            else             { int u = c - 24; src = Bi + (size_t)(n0 + u * 8 + s_lr) * C_DIM + k0 + s_c * 8; dst = sm + 12288 + u * 512; }
            GLOAD_LDS16(src, dst);
        }
        __syncthreads();
#pragma unroll
        for (int kh = 0; kh < 2; kh++) {
            bf16x8 ar[2], ai_[2], br_[2], bi_[2], bn_[2];
#pragma unroll
            for (int i = 0; i < 2; i++) {
                ar[i]  = frag_sw(sm,        wm + i * 16 + lm, kh * 4 + quad);
                ai_[i] = frag_sw(sm + 4096, wm + i * 16 + lm, kh * 4 + quad);
            }
#pragma unroll
            for (int j = 0; j < 2; j++) {
                br_[j] = frag_sw(sm + 8192,  wn + j * 16 + lm, kh * 4 + quad);
                bi_[j] = frag_sw(sm + 12288, wn + j * 16 + lm, kh * 4 + quad);
                bn_[j] = neg8(bi_[j]);
            }
#pragma unroll
            for (int i = 0; i < 2; i++)
#pragma unroll
                for (int j = 0; j < 2; j++) {
                    accr[i][j] = MFMA16(ar[i],  br_[j], accr[i][j]);
                    accr[i][j] = MFMA16(ai_[i], bn_[j], accr[i][j]);
                    acci[i][j] = MFMA16(ar[i],  bi_[j], acci[i][j]);
                    acci[i][j] = MFMA16(ai_[i], br_[j], acci[i][j]);
                }
        }
        __syncthreads();
    }
#pragma unroll
    for (int i = 0; i < 2; i++)
#pragma unroll
        for (int j = 0; j < 2; j++) {
            int n = n0 + wn + j * 16 + lm;
            float2 bv = *(const float2*)&bias[2 * n];
#pragma unroll
            for (int r = 0; r < 4; r++) {
                int m = m0 + wm + i * 16 + quad * 4 + r;
                *(float2*)&Y[((size_t)m * C_DIM + n) * 2] =
                    make_float2(accr[i][j][r] + bv.x, acci[i][j][r] + bv.y);
            }
        }
}

// ---------------------------------------------------------------------------
// MFMA flash attention, S^T layout, 8 waves (2 s-halves x 4 q-groups).
// Q/K planes [B,H,T,64], V planes [B,H,64,T]. Out: ABr/ABi [B*T][1024].
// LDS 48 KB. Pl: padded stride-40 layout (20-bank rows -> conflict-free).
// ---------------------------------------------------------------------------
__global__ __launch_bounds__(512, 4)
void attn_mfma(const bf16* __restrict__ Qpr, const bf16* __restrict__ Qpi,
               const bf16* __restrict__ Kpr, const bf16* __restrict__ Kpi,
               const bf16* __restrict__ Vtr, const bf16* __restrict__ Vti,
               bf16* __restrict__ ABr, bf16* __restrict__ ABi)
{
    __shared__ __attribute__((aligned(16))) bf16 smem[24576];  // 48 KB
    const int t = threadIdx.x, lane = t & 63, w = t >> 6;
    const int qg = w & 3, sh = w >> 2;
    const int lm = lane & 15, quad = lane >> 4;
    const int q0 = blockIdx.x * 64;
    const int h = blockIdx.y, b = blockIdx.z;
    const size_t hb = (size_t)(b * NH_ + h) * T_SEQ * H_DIM;
    const int s_lr = lane >> 3, s_c = (lane & 7) ^ s_lr;        // 8-chunk swizzle
    const int lr4 = lane >> 2, sc4 = ((lane & 3) ^ (lr4 & 3)) * 8;  // 4-chunk swizzle

    // stage Q (64 rows x 64), 16 chunks over 8 waves
    {
        const bf16* gq = (sh == 0 ? Qpr : Qpi) + hb + (size_t)q0 * H_DIM;
        bf16* lq = smem + sh * 4096;
#pragma unroll
        for (int j = 0; j < 2; j++) {
            int cc = qg * 2 + j;
            GLOAD_LDS16(gq + (cc * 8 + s_lr) * H_DIM + s_c * 8, lq + cc * 512);
        }
    }
    __syncthreads();

    bf16x8 qfr[2], qfi[2], nqfr[2];
#pragma unroll
    for (int kh = 0; kh < 2; kh++) {
        qfr[kh]  = frag_sw(smem,        qg * 16 + lm, kh * 4 + quad);
        qfi[kh]  = frag_sw(smem + 4096, qg * 16 + lm, kh * 4 + quad);
        nqfr[kh] = neg8(qfr[kh]);
    }

    bf16* Ks_r = smem + 8192 + sh * 8192;
    bf16* Ks_i = Ks_r + 2048;
    bf16* Vs_r = Ks_r + 4096;
    bf16* Vs_i = Ks_r + 6144;
    bf16* Pl   = smem;                     // 128 rows x 40 (32 + 8 pad), aliases Q
    const int prow = sh * 64 + qg * 16 + lm;

    f32x4 Or[4], Oi[4];
#pragma unroll
    for (int nt = 0; nt < 4; nt++) { Or[nt] = (f32x4)0.f; Oi[nt] = (f32x4)0.f; }
    float mold = 0.f, lsum = 0.f;

    for (int it = 0; it < 16; it++) {
        const int s0 = it * 32 + sh * 512;
        __syncthreads();
        {   // wave (qg, sh) stages plane qg of its s-half: 4 chunks
            if (qg < 2) {
                const bf16* gsrc = (qg == 0 ? Kpr : Kpi) + hb + (size_t)s0 * H_DIM;
                bf16* ldst = (qg == 0) ? Ks_r : Ks_i;
#pragma unroll
                for (int cc = 0; cc < 4; cc++)
                    GLOAD_LDS16(gsrc + (cc * 8 + s_lr) * H_DIM + s_c * 8, ldst + cc * 512);
            } else {
                const bf16* gsrc = (qg == 2 ? Vtr : Vti) + hb + s0;
                bf16* ldst = (qg == 2) ? Vs_r : Vs_i;
#pragma unroll
                for (int cc = 0; cc < 4; cc++)
                    GLOAD_LDS16(gsrc + (size_t)(cc * 16 + lr4) * T_SEQ + sc4, ldst + cc * 512);
            }
        }
        __syncthreads();

        // S^T scores: A = K frags (m = s), B = Q frags (n = q)
        float sc[2][4];
#pragma unroll
        for (int ct = 0; ct < 2; ct++) {
            f32x4 sre = (f32x4)0.f, sim = (f32x4)0.f;
#pragma unroll
            for (int kh = 0; kh < 2; kh++) {
                bf16x8 kr = frag_sw(Ks_r, ct * 16 + lm, kh * 4 + quad);
                bf16x8 ki = frag_sw(Ks_i, ct * 16 + lm, kh * 4 + quad);
                sre = MFMA16(kr, qfr[kh],  sre);
                sre = MFMA16(ki, qfi[kh],  sre);
                sim = MFMA16(kr, qfi[kh],  sim);
                sim = MFMA16(ki, nqfr[kh], sim);
            }
#pragma unroll
            for (int r = 0; r < 4; r++)
                sc[ct][r] = sqrtf(sre[r] * sre[r] + sim[r] * sim[r]) * SCL;
        }

        // online softmax, state per lane (q = lm), reduce across quads
        float mx = sc[0][0];
#pragma unroll
        for (int ct = 0; ct < 2; ct++)
#pragma unroll
            for (int r = 0; r < 4; r++) mx = fmaxf(mx, sc[ct][r]);
        mx = fmaxf(mx, __shfl_xor(mx, 16));
        mx = fmaxf(mx, __shfl_xor(mx, 32));
        float mnew = fmaxf(mold, mx);
        float alpha = exp2f(mold - mnew);
        float ps = 0.f;
#pragma unroll
        for (int ct = 0; ct < 2; ct++) {
            bf16x4 pk;
#pragma unroll
            for (int r = 0; r < 4; r++) {
                float p = exp2f(sc[ct][r] - mnew);
                ps += p;
                pk[r] = (bf16)p;
            }
            *(bf16x4*)&Pl[prow * 40 + ct * 16 + quad * 4] = pk;
        }
        ps += __shfl_xor(ps, 16);
        ps += __shfl_xor(ps, 32);
        lsum = lsum * alpha + ps;
        mold = mnew;

        float aO[4];
#pragma unroll
        for (int r = 0; r < 4; r++)
            aO[r] = __shfl(alpha, (quad << 4) + quad * 4 + r, 64);
#pragma unroll
        for (int nt = 0; nt < 4; nt++)
#pragma unroll
            for (int r = 0; r < 4; r++) { Or[nt][r] *= aO[r]; Oi[nt][r] *= aO[r]; }

        // PV: A = P (m = q), B = V^T frags
        bf16x8 pf = *(const bf16x8*)&Pl[prow * 40 + quad * 8];
#pragma unroll
        for (int nt = 0; nt < 4; nt++) {
            Or[nt] = MFMA16(pf, frag_sw4(Vs_r, nt * 16 + lm, quad), Or[nt]);
            Oi[nt] = MFMA16(pf, frag_sw4(Vs_i, nt * 16 + lm, quad), Oi[nt]);
        }
    }

    // merge s-halves: sh1 -> LDS, sh0 combines and writes out
    float* Of = (float*)(smem + 8192);   // 32 KB staging region
    float* ml = (float*)smem;            // Pl region, dead
    __syncthreads();
    if (sh == 1) {
#pragma unroll
        for (int nt = 0; nt < 4; nt++)
#pragma unroll
            for (int r = 0; r < 4; r++) {
                Of[((qg * 2 + 0) * 16 + quad * 4 + r) * 64 + nt * 16 + lm] = Or[nt][r];
                Of[((qg * 2 + 1) * 16 + quad * 4 + r) * 64 + nt * 16 + lm] = Oi[nt][r];
            }
        if (quad == 0) *(float2*)&ml[(qg * 16 + lm) * 2] = make_float2(mold, lsum);
    }
    __syncthreads();
    if (sh == 0) {
        float2 m2 = *(const float2*)&ml[(qg * 16 + lm) * 2];
        float mn = fmaxf(mold, m2.x);
        float a1 = exp2f(mold - mn), a2 = exp2f(m2.x - mn);
        lsum = a1 * lsum + a2 * m2.y;
        float a1r[4], a2r[4], linv[4];
        float lv = 1.f / lsum;
#pragma unroll
        for (int r = 0; r < 4; r++) {
            int src = (quad << 4) + quad * 4 + r;
            a1r[r]  = __shfl(a1, src, 64);
            a2r[r]  = __shfl(a2, src, 64);
            linv[r] = __shfl(lv, src, 64);
        }
        size_t mbase = (size_t)(b * T_SEQ + q0 + qg * 16 + quad * 4) * C_DIM;
        int colb = h * H_DIM + lm;
#pragma unroll
        for (int nt = 0; nt < 4; nt++)
#pragma unroll
            for (int r = 0; r < 4; r++) {
                float orv = a1r[r] * Or[nt][r] +
                            a2r[r] * Of[((qg * 2 + 0) * 16 + quad * 4 + r) * 64 + nt * 16 + lm];
                float oiv = a1r[r] * Oi[nt][r] +
                            a2r[r] * Of[((qg * 2 + 1) * 16 + quad * 4 + r) * 64 + nt * 16 + lm];
                size_t o = mbase + (size_t)r * C_DIM + colb + nt * 16;
                ABr[o] = (bf16)(orv * linv[r]);
                ABi[o] = (bf16)(oiv * linv[r]);
            }
    }
}

// ---------------------------------------------------------------------------
extern "C" void kernel_launch(void* const* d_in, const int* in_sizes, int n_in,
                              void* d_out, int out_size, void* d_ws, size_t ws_size,
                              hipStream_t stream) {
    const float* x  = (const float*)d_in[0];
    const float* wq = (const float*)d_in[1];
    const float* bq = (const float*)d_in[2];
    const float* wk = (const float*)d_in[3];
    const float* bk = (const float*)d_in[4];
    const float* wv = (const float*)d_in[5];
    const float* bv = (const float*)d_in[6];
    const float* wo = (const float*)d_in[7];
    const float* bo = (const float*)d_in[8];

    float* rope = (float*)d_ws;                       // 131072 floats (512 KB)
    bf16* w = (bf16*)(rope + 131072);
    const size_t MSZ = (size_t)2048 * 1024;
    const size_t WSZ = (size_t)1024 * 1024;
    const size_t PSZ = (size_t)2 * NH_ * T_SEQ * H_DIM;

    bf16 *Xr = w, *Xi = Xr + MSZ;
    bf16 *Wqr = Xi + MSZ,  *Wqi = Wqr + WSZ;
    bf16 *Wkr = Wqi + WSZ, *Wki = Wkr + WSZ;
    bf16 *Wvr = Wki + WSZ, *Wvi = Wvr + WSZ;
    bf16 *Wor = Wvi + WSZ, *Woi = Wor + WSZ;
    bf16 *Qr = Woi + WSZ, *Qi = Qr + PSZ;
    bf16 *Kr = Qi + PSZ,  *Ki = Kr + PSZ;
    bf16 *Vr = Ki + PSZ,  *Vi = Vr + PSZ;
    bf16 *ABr = Vi + PSZ, *ABi = ABr + MSZ;

    split_all<<<dim3(2048, 6), 256, 0, stream>>>(x, wq, wk, wv, wo,
        Xr, Xi, Wqr, Wqi, Wkr, Wki, Wvr, Wvi, Wor, Woi, rope);

    qkv_gemm<<<dim3(16, 16, 3), 256, 0, stream>>>(
        Xr, Xi, Wqr, Wqi, Wkr, Wki, Wvr, Wvi, bq, bk, bv, rope,
        Qr, Qi, Kr, Ki, Vr, Vi);

    attn_mfma<<<dim3(16, 16, 2), 512, 0, stream>>>(
        Qr, Qi, Kr, Ki, Vr, Vi, ABr, ABi);

    out_gemm<<<dim3(16, 32), 256, 0, stream>>>(ABr, ABi, Wor, Woi, bo, (float*)d_out);
}

// Round 7
// 217.014 us; speedup vs baseline: 1.2309x; 1.0967x over previous
//
#include <hip/hip_runtime.h>
#include <math.h>

#define T_SEQ  1024
#define C_DIM  1024
#define NH_    16
#define H_DIM  64
#define SCL    (0.125f * 1.4426950408889634f)   // 1/sqrt(64) folded with log2e

typedef __bf16 bf16;
typedef __bf16 bf16x4 __attribute__((ext_vector_type(4)));
typedef __bf16 bf16x8 __attribute__((ext_vector_type(8)));
typedef float  f32x4  __attribute__((ext_vector_type(4)));

#define MFMA16(a, b, c) __builtin_amdgcn_mfma_f32_16x16x32_bf16(a, b, c, 0, 0, 0)

#define GLOAD_LDS16(g, l) __builtin_amdgcn_global_load_lds( \
    (const __attribute__((address_space(1))) void*)(g),     \
    (__attribute__((address_space(3))) void*)(l), 16, 0, 0)

__device__ __forceinline__ bf16x8 neg8(bf16x8 x) {
    union { bf16x8 v; unsigned int u[4]; } t;
    t.v = x;
    t.u[0] ^= 0x80008000u; t.u[1] ^= 0x80008000u;
    t.u[2] ^= 0x80008000u; t.u[3] ^= 0x80008000u;
    return t.v;
}

// fragment read from XOR-8-chunk-swizzled [rows][64] bf16 plane
__device__ __forceinline__ bf16x8 frag_sw(const bf16* plane, int row, int chunk) {
    int c = chunk ^ (row & 7);
    return *(const bf16x8*)&plane[row * 64 + c * 8];
}
// fragment read from XOR-4-chunk-swizzled [rows][32] bf16 plane
__device__ __forceinline__ bf16x8 frag_sw4(const bf16* plane, int row, int chunk) {
    int c = chunk ^ (row & 3);
    return *(const bf16x8*)&plane[row * 32 + c * 8];
}

// ---------------------------------------------------------------------------
// splits: fp32 complex [R][1024][2] -> bf16 planes (re, im), 8 complex/thread.
// z==5 builds the RoPE phasor table.
// ---------------------------------------------------------------------------
__global__ __launch_bounds__(256)
void split_all(const float* __restrict__ x,  const float* __restrict__ wq,
               const float* __restrict__ wk, const float* __restrict__ wv,
               const float* __restrict__ wo,
               bf16* Xr, bf16* Xi, bf16* Wqr, bf16* Wqi, bf16* Wkr, bf16* Wki,
               bf16* Wvr, bf16* Wvi, bf16* Wor, bf16* Woi,
               float* __restrict__ rope)
{
    int z = blockIdx.y;
    if (z == 5) {
        if (blockIdx.x >= 256) return;
        int idx = blockIdx.x * 256 + threadIdx.x;   // 65536
        int tp = idx >> 6, d = idx & 63;
        float invf = exp2f((float)d * -0.2076205059304601f);
        float fr = (float)tp * invf;
        float sn, cs; sincosf(fr, &sn, &cs);
        *(float2*)&rope[(size_t)idx * 2] = make_float2(cs, sn);
        return;
    }
    if (z > 0 && blockIdx.x >= 512) return;
    const float* in; bf16 *pr, *pi;
    if      (z == 0) { in = x;  pr = Xr;  pi = Xi;  }
    else if (z == 1) { in = wq; pr = Wqr; pi = Wqi; }
    else if (z == 2) { in = wk; pr = Wkr; pi = Wki; }
    else if (z == 3) { in = wv; pr = Wvr; pi = Wvi; }
    else             { in = wo; pr = Wor; pi = Woi; }
    int idx = (blockIdx.x * 256 + threadIdx.x) * 8;   // 8 complex per thread
    bf16x8 r, im;
#pragma unroll
    for (int j = 0; j < 4; j++) {
        float4 v = *(const float4*)(in + (size_t)idx * 2 + j * 4);
        r[2*j]   = (bf16)v.x; im[2*j]   = (bf16)v.y;
        r[2*j+1] = (bf16)v.z; im[2*j+1] = (bf16)v.w;
    }
    *(bf16x8*)(pr + idx) = r;
    *(bf16x8*)(pi + idx) = im;
}

// ---------------------------------------------------------------------------
// 128x64 complex GEMM core, BK=64. smem passed in (single shared alloc).
// mode 1: q/k planes [B,H,T,64] + RoPE.  mode 2: v planes transposed [B,H,64,T].
// ---------------------------------------------------------------------------
__device__ __forceinline__ void cgemm128(
    bf16* __restrict__ smem,
    const bf16* __restrict__ Ar, const bf16* __restrict__ Ai,
    const bf16* __restrict__ Br, const bf16* __restrict__ Bi,
    const float* __restrict__ bias, const float* __restrict__ rope,
    bf16* __restrict__ Yr, bf16* __restrict__ Yi, int m0, int n0, int mode)
{
    const int t = threadIdx.x, lane = t & 63, wave = t >> 6;
    const int wm = (wave >> 1) * 64, wn = (wave & 1) * 32;
    const int lm = lane & 15, quad = lane >> 4;
    const int s_lr = lane >> 3, s_c = (lane & 7) ^ s_lr;

    f32x4 accr[4][2], acci[4][2];
#pragma unroll
    for (int i = 0; i < 4; i++)
#pragma unroll
        for (int j = 0; j < 2; j++) { accr[i][j] = (f32x4)0.f; acci[i][j] = (f32x4)0.f; }

    for (int k0 = 0; k0 < C_DIM; k0 += 64) {
#pragma unroll
        for (int j = 0; j < 12; j++) {
            int c = wave + 4 * j;
            const bf16* src; bf16* dst;
            if (c < 16)      {             src = Ar + (size_t)(m0 + c * 8 + s_lr) * C_DIM + k0 + s_c * 8; dst = smem + c * 512; }
            else if (c < 32) { int u = c - 16; src = Ai + (size_t)(m0 + u * 8 + s_lr) * C_DIM + k0 + s_c * 8; dst = smem + 8192 + u * 512; }
            else if (c < 40) { int u = c - 32; src = Br + (size_t)(n0 + u * 8 + s_lr) * C_DIM + k0 + s_c * 8; dst = smem + 16384 + u * 512; }
            else             { int u = c - 40; src = Bi + (size_t)(n0 + u * 8 + s_lr) * C_DIM + k0 + s_c * 8; dst = smem + 20480 + u * 512; }
            GLOAD_LDS16(src, dst);
        }
        __syncthreads();

#pragma unroll
        for (int kh = 0; kh < 2; kh++) {
            bf16x8 ar[4], ai_[4], br_[2], bi_[2], bn_[2];
#pragma unroll
            for (int i = 0; i < 4; i++) {
                ar[i]  = frag_sw(smem,        wm + i * 16 + lm, kh * 4 + quad);
                ai_[i] = frag_sw(smem + 8192, wm + i * 16 + lm, kh * 4 + quad);
            }
#pragma unroll
            for (int j = 0; j < 2; j++) {
                br_[j] = frag_sw(smem + 16384, wn + j * 16 + lm, kh * 4 + quad);
                bi_[j] = frag_sw(smem + 20480, wn + j * 16 + lm, kh * 4 + quad);
                bn_[j] = neg8(bi_[j]);
            }
#pragma unroll
            for (int i = 0; i < 4; i++)
#pragma unroll
                for (int j = 0; j < 2; j++) {
                    accr[i][j] = MFMA16(ar[i],  br_[j], accr[i][j]);
                    accr[i][j] = MFMA16(ai_[i], bn_[j], accr[i][j]);
                    acci[i][j] = MFMA16(ar[i],  bi_[j], acci[i][j]);
                    acci[i][j] = MFMA16(ai_[i], br_[j], acci[i][j]);
                }
        }
        __syncthreads();
    }

    const int h = n0 >> 6, bb = m0 >> 10, tbase = m0 & (T_SEQ - 1);

    if (mode == 1) {
#pragma unroll
        for (int i = 0; i < 4; i++)
#pragma unroll
            for (int j = 0; j < 2; j++) {
                int d = wn + j * 16 + lm;
                float2 bv = *(const float2*)&bias[2 * (n0 + d)];
#pragma unroll
                for (int r = 0; r < 4; r++) {
                    int tpos = tbase + wm + i * 16 + quad * 4 + r;
                    float2 ph = *(const float2*)&rope[((size_t)tpos * H_DIM + d) * 2];
                    float yr = accr[i][j][r] + bv.x;
                    float yi = acci[i][j][r] + bv.y;
                    accr[i][j][r] = yr * ph.x - yi * ph.y;
                    acci[i][j][r] = yr * ph.y + yi * ph.x;
                }
            }
        bf16* dsts[2] = { Yr, Yi };
#pragma unroll
        for (int pass = 0; pass < 2; pass++) {
            __syncthreads();
#pragma unroll
            for (int i = 0; i < 4; i++)
#pragma unroll
                for (int j = 0; j < 2; j++)
#pragma unroll
                    for (int r = 0; r < 4; r++)
                        smem[(wm + i * 16 + quad * 4 + r) * 72 + wn + j * 16 + lm] =
                            (bf16)(pass ? acci[i][j][r] : accr[i][j][r]);
            __syncthreads();
            bf16* dst = dsts[pass] + ((size_t)(bb * NH_ + h) * T_SEQ + tbase) * H_DIM;
#pragma unroll
            for (int p = 0; p < 4; p++) {
                int ch = t + 256 * p;
                int row = ch >> 3, o = (ch & 7) * 8;
                *(bf16x8*)&dst[row * H_DIM + o] = *(const bf16x8*)&smem[row * 72 + o];
            }
        }
    } else {
        bf16* dsts[2] = { Yr, Yi };
#pragma unroll
        for (int pass = 0; pass < 2; pass++) {
            __syncthreads();
#pragma unroll
            for (int i = 0; i < 4; i++)
#pragma unroll
                for (int j = 0; j < 2; j++) {
                    int d = wn + j * 16 + lm;
                    float2 bv = *(const float2*)&bias[2 * (n0 + d)];
                    float bb2 = pass ? bv.y : bv.x;
                    bf16x4 pk;
#pragma unroll
                    for (int r = 0; r < 4; r++)
                        pk[r] = (bf16)((pass ? acci[i][j][r] : accr[i][j][r]) + bb2);
                    *(bf16x4*)&smem[d * 136 + wm + i * 16 + quad * 4] = pk;
                }
            __syncthreads();
            bf16* dst = dsts[pass] + ((size_t)(bb * NH_ + h) * H_DIM) * T_SEQ + tbase;
#pragma unroll
            for (int p = 0; p < 4; p++) {
                int ch = t + 256 * p;
                int row = ch >> 4, o = (ch & 15) * 8;
                *(bf16x8*)&dst[(size_t)row * T_SEQ + o] = *(const bf16x8*)&smem[row * 136 + o];
            }
        }
    }
}

__global__ __launch_bounds__(256, 3)
void qkv_gemm(const bf16* __restrict__ Xr, const bf16* __restrict__ Xi,
              const bf16* __restrict__ Wqr, const bf16* __restrict__ Wqi,
              const bf16* __restrict__ Wkr, const bf16* __restrict__ Wki,
              const bf16* __restrict__ Wvr, const bf16* __restrict__ Wvi,
              const float* __restrict__ bq, const float* __restrict__ bk,
              const float* __restrict__ bv, const float* __restrict__ rope,
              bf16* Qr, bf16* Qi, bf16* Kr, bf16* Ki, bf16* Vr, bf16* Vi)
{
    __shared__ __attribute__((aligned(16))) bf16 smem[24576];  // ONE 48 KB alloc
    int m0 = blockIdx.y * 128, n0 = blockIdx.x * 64;
    const bf16 *Br, *Bi; const float* bias; bf16 *Yr, *Yi; int mode;
    if (blockIdx.z == 0)      { Br = Wqr; Bi = Wqi; bias = bq; Yr = Qr; Yi = Qi; mode = 1; }
    else if (blockIdx.z == 1) { Br = Wkr; Bi = Wki; bias = bk; Yr = Kr; Yi = Ki; mode = 1; }
    else                      { Br = Wvr; Bi = Wvi; bias = bv; Yr = Vr; Yi = Vi; mode = 2; }
    cgemm128(smem, Xr, Xi, Br, Bi, bias, rope, Yr, Yi, m0, n0, mode);
}

// ---------------------------------------------------------------------------
// 64x64 complex GEMM, BK=64 (final projection, fp32 interleaved out).
// ---------------------------------------------------------------------------
__global__ __launch_bounds__(256, 4)
void out_gemm(const bf16* __restrict__ Ar, const bf16* __restrict__ Ai,
              const bf16* __restrict__ Br, const bf16* __restrict__ Bi,
              const float* __restrict__ bias, float* __restrict__ Y)
{
    __shared__ __attribute__((aligned(16))) bf16 sm[16384];   // 32 KB
    const int t = threadIdx.x, lane = t & 63, wave = t >> 6;
    const int lm = lane & 15, quad = lane >> 4;
    const int s_lr = lane >> 3, s_c = (lane & 7) ^ s_lr;
    const int wm = (wave >> 1) * 32, wn = (wave & 1) * 32;
    const int m0 = blockIdx.y * 64, n0 = blockIdx.x * 64;

    f32x4 accr[2][2], acci[2][2];
#pragma unroll
    for (int i = 0; i < 2; i++)
#pragma unroll
        for (int j = 0; j < 2; j++) { accr[i][j] = (f32x4)0.f; acci[i][j] = (f32x4)0.f; }

    for (int k0 = 0; k0 < C_DIM; k0 += 64) {
#pragma unroll
        for (int j = 0; j < 8; j++) {
            int c = wave + 4 * j;
            const bf16* src; bf16* dst;
            if (c < 8)       {             src = Ar + (size_t)(m0 + c * 8 + s_lr) * C_DIM + k0 + s_c * 8; dst = sm + c * 512; }
            else if (c < 16) { int u = c - 8;  src = Ai + (size_t)(m0 + u * 8 + s_lr) * C_DIM + k0 + s_c * 8; dst = sm + 4096 + u * 512; }
            else if (c < 24) { int u = c - 16; src = Br + (size_t)(n0 + u * 8 + s_lr) * C_DIM + k0 + s_c * 8; dst = sm + 8192 + u * 512; }
            else             { int u = c - 24; src = Bi + (size_t)(n0 + u * 8 + s_lr) * C_DIM + k0 + s_c * 8; dst = sm + 12288 + u * 512; }
            GLOAD_LDS16(src, dst);
        }
        __syncthreads();
#pragma unroll
        for (int kh = 0; kh < 2; kh++) {
            bf16x8 ar[2], ai_[2], br_[2], bi_[2], bn_[2];
#pragma unroll
            for (int i = 0; i < 2; i++) {
                ar[i]  = frag_sw(sm,        wm + i * 16 + lm, kh * 4 + quad);
                ai_[i] = frag_sw(sm + 4096, wm + i * 16 + lm, kh * 4 + quad);
            }
#pragma unroll
            for (int j = 0; j < 2; j++) {
                br_[j] = frag_sw(sm + 8192,  wn + j * 16 + lm, kh * 4 + quad);
                bi_[j] = frag_sw(sm + 12288, wn + j * 16 + lm, kh * 4 + quad);
                bn_[j] = neg8(bi_[j]);
            }
#pragma unroll
            for (int i = 0; i < 2; i++)
#pragma unroll
                for (int j = 0; j < 2; j++) {
                    accr[i][j] = MFMA16(ar[i],  br_[j], accr[i][j]);
                    accr[i][j] = MFMA16(ai_[i], bn_[j], accr[i][j]);
                    acci[i][j] = MFMA16(ar[i],  bi_[j], acci[i][j]);
                    acci[i][j] = MFMA16(ai_[i], br_[j], acci[i][j]);
                }
        }
        __syncthreads();
    }
#pragma unroll
    for (int i = 0; i < 2; i++)
#pragma unroll
        for (int j = 0; j < 2; j++) {
            int n = n0 + wn + j * 16 + lm;
            float2 bv = *(const float2*)&bias[2 * n];
#pragma unroll
            for (int r = 0; r < 4; r++) {
                int m = m0 + wm + i * 16 + quad * 4 + r;
                *(float2*)&Y[((size_t)m * C_DIM + n) * 2] =
                    make_float2(accr[i][j][r] + bv.x, acci[i][j][r] + bv.y);
            }
        }
}

// ---------------------------------------------------------------------------
// MFMA flash attention v3: double-buffered K/V (one barrier/iter), no-max
// softmax (scores bounded -> exp2 safe), P C->A via ds_bpermute (no LDS).
// 8 waves = 2 s-halves x 4 q-groups. LDS 64 KB = 2 bufs x (2 halves x 16 KB).
// Q staged into buf1 pre-loop, then lives in registers.
// ---------------------------------------------------------------------------
__global__ __launch_bounds__(512, 4)
void attn_mfma(const bf16* __restrict__ Qpr, const bf16* __restrict__ Qpi,
               const bf16* __restrict__ Kpr, const bf16* __restrict__ Kpi,
               const bf16* __restrict__ Vtr, const bf16* __restrict__ Vti,
               bf16* __restrict__ ABr, bf16* __restrict__ ABi)
{
    __shared__ __attribute__((aligned(16))) bf16 smem[32768];  // 64 KB
    const int t = threadIdx.x, lane = t & 63, w = t >> 6;
    const int qg = w & 3, sh = w >> 2;
    const int lm = lane & 15, quad = lane >> 4;
    const int q0 = blockIdx.x * 64;
    const int h = blockIdx.y, b = blockIdx.z;
    const size_t hb = (size_t)(b * NH_ + h) * T_SEQ * H_DIM;
    const int s_lr = lane >> 3, s_c = (lane & 7) ^ s_lr;
    const int lr4 = lane >> 2, sc4 = ((lane & 3) ^ (lr4 & 3)) * 8;

    // stage Q (64x64 per plane) into buf1 region, then hold frags in regs
    {
        const bf16* gq = (sh ? Qpi : Qpr) + hb + (size_t)q0 * H_DIM;
        bf16* lq = smem + 16384 + sh * 4096;
#pragma unroll
        for (int j = 0; j < 2; j++) {
            int cc = qg * 2 + j;
            GLOAD_LDS16(gq + (cc * 8 + s_lr) * H_DIM + s_c * 8, lq + cc * 512);
        }
    }
    __syncthreads();

    bf16x8 qfr[2], qfi[2], nqfr[2];
#pragma unroll
    for (int kh = 0; kh < 2; kh++) {
        qfr[kh]  = frag_sw(smem + 16384, qg * 16 + lm, kh * 4 + quad);
        qfi[kh]  = frag_sw(smem + 20480, qg * 16 + lm, kh * 4 + quad);
        nqfr[kh] = neg8(qfr[kh]);
    }

    // stage tile 0 into buf0 (per-wave plane assignment)
#pragma unroll
    for (int pre = 0; pre < 1; pre++) {
        const int S = sh * 512;
        bf16* bd = smem + sh * 8192;
        if (qg < 2) {
            const bf16* g = (qg ? Kpi : Kpr) + hb + (size_t)S * H_DIM;
            bf16* d = bd + (qg ? 2048 : 0);
#pragma unroll
            for (int cc = 0; cc < 4; cc++)
                GLOAD_LDS16(g + (cc * 8 + s_lr) * H_DIM + s_c * 8, d + cc * 512);
        } else {
            const bf16* g = (qg == 2 ? Vtr : Vti) + hb + S;
            bf16* d = bd + (qg == 2 ? 4096 : 6144);
#pragma unroll
            for (int cc = 0; cc < 4; cc++)
                GLOAD_LDS16(g + (size_t)(cc * 16 + lr4) * T_SEQ + sc4, d + cc * 512);
        }
    }

    f32x4 Or[4], Oi[4];
#pragma unroll
    for (int nt = 0; nt < 4; nt++) { Or[nt] = (f32x4)0.f; Oi[nt] = (f32x4)0.f; }
    float lsum = 0.f;
    const int idxA = (((2 * quad) & 3) * 16 + lm) * 4;   // bpermute byte idx
    const int idxB = idxA + 64;
    const bool hisel = quad >= 2;

    for (int it = 0; it < 16; it++) {
        __syncthreads();   // drains stage(it) issued last iter; all reads of buf[(it+1)&1] done
        if (it < 15) {     // stage tile it+1 into the other buffer
            const int S = (it + 1) * 32 + sh * 512;
            bf16* bd = smem + ((it + 1) & 1) * 16384 + sh * 8192;
            if (qg < 2) {
                const bf16* g = (qg ? Kpi : Kpr) + hb + (size_t)S * H_DIM;
                bf16* d = bd + (qg ? 2048 : 0);
#pragma unroll
                for (int cc = 0; cc < 4; cc++)
                    GLOAD_LDS16(g + (cc * 8 + s_lr) * H_DIM + s_c * 8, d + cc * 512);
            } else {
                const bf16* g = (qg == 2 ? Vtr : Vti) + hb + S;
                bf16* d = bd + (qg == 2 ? 4096 : 6144);
#pragma unroll
                for (int cc = 0; cc < 4; cc++)
                    GLOAD_LDS16(g + (size_t)(cc * 16 + lr4) * T_SEQ + sc4, d + cc * 512);
            }
        }
        const bf16* buf = smem + (it & 1) * 16384 + sh * 8192;

        // ---- S^T scores (A = K frags, B = Q frags), p = exp2(|s|*SCL) ----
        union { unsigned int u[2]; bf16 b[4]; } pk[2];
#pragma unroll
        for (int ct = 0; ct < 2; ct++) {
            f32x4 sre = (f32x4)0.f, sim = (f32x4)0.f;
#pragma unroll
            for (int kh = 0; kh < 2; kh++) {
                bf16x8 kr = frag_sw(buf,        ct * 16 + lm, kh * 4 + quad);
                bf16x8 ki = frag_sw(buf + 2048, ct * 16 + lm, kh * 4 + quad);
                sre = MFMA16(kr, qfr[kh],  sre);
                sre = MFMA16(ki, qfi[kh],  sre);
                sim = MFMA16(kr, qfi[kh],  sim);
                sim = MFMA16(ki, nqfr[kh], sim);
            }
#pragma unroll
            for (int r = 0; r < 4; r++) {
                float p = exp2f(sqrtf(sre[r] * sre[r] + sim[r] * sim[r]) * SCL);
                lsum += p;
                pk[ct].b[r] = (bf16)p;
            }
        }

        // ---- P C-layout -> A-layout via bpermute (no LDS round trip) ----
        union { unsigned int u[4]; bf16x8 v; } pf;
        {
            int a0 = __builtin_amdgcn_ds_bpermute(idxA, (int)pk[0].u[0]);
            int a1 = __builtin_amdgcn_ds_bpermute(idxA, (int)pk[1].u[0]);
            int b0 = __builtin_amdgcn_ds_bpermute(idxA, (int)pk[0].u[1]);
            int b1 = __builtin_amdgcn_ds_bpermute(idxA, (int)pk[1].u[1]);
            int c0 = __builtin_amdgcn_ds_bpermute(idxB, (int)pk[0].u[0]);
            int c1 = __builtin_amdgcn_ds_bpermute(idxB, (int)pk[1].u[0]);
            int d0 = __builtin_amdgcn_ds_bpermute(idxB, (int)pk[0].u[1]);
            int d1 = __builtin_amdgcn_ds_bpermute(idxB, (int)pk[1].u[1]);
            pf.u[0] = (unsigned int)(hisel ? a1 : a0);
            pf.u[1] = (unsigned int)(hisel ? b1 : b0);
            pf.u[2] = (unsigned int)(hisel ? c1 : c0);
            pf.u[3] = (unsigned int)(hisel ? d1 : d0);
        }

        // ---- PV: O[q][d] += P @ V^T ----
#pragma unroll
        for (int nt = 0; nt < 4; nt++) {
            Or[nt] = MFMA16(pf.v, frag_sw4(buf + 4096, nt * 16 + lm, quad), Or[nt]);
            Oi[nt] = MFMA16(pf.v, frag_sw4(buf + 6144, nt * 16 + lm, quad), Oi[nt]);
        }
    }

    // reduce lsum across quads (full 32-s tile per iter already per-lane-summed)
    lsum += __shfl_xor(lsum, 16);
    lsum += __shfl_xor(lsum, 32);

    // merge the two s-halves: sh1 dumps to LDS, sh0 adds, normalizes, writes
    __syncthreads();                       // everyone done with both buffers
    float* Of  = (float*)smem;             // 128 rows x 66 floats (~33 KB)
    float* lsc = Of + 128 * 66;            // 64 floats
    if (sh == 1) {
#pragma unroll
        for (int nt = 0; nt < 4; nt++)
#pragma unroll
            for (int r = 0; r < 4; r++) {
                Of[((qg * 2 + 0) * 16 + quad * 4 + r) * 66 + nt * 16 + lm] = Or[nt][r];
                Of[((qg * 2 + 1) * 16 + quad * 4 + r) * 66 + nt * 16 + lm] = Oi[nt][r];
            }
        if (quad == 0) lsc[qg * 16 + lm] = lsum;
    }
    __syncthreads();
    if (sh == 0) {
        float ltot = lsum + lsc[qg * 16 + lm];
        float lv = 1.f / ltot;
        float linv[4];
#pragma unroll
        for (int r = 0; r < 4; r++)
            linv[r] = __shfl(lv, (quad << 4) + quad * 4 + r, 64);
        size_t mbase = (size_t)(b * T_SEQ + q0 + qg * 16 + quad * 4) * C_DIM;
        int colb = h * H_DIM + lm;
#pragma unroll
        for (int nt = 0; nt < 4; nt++)
#pragma unroll
            for (int r = 0; r < 4; r++) {
                float orv = Or[nt][r] + Of[((qg * 2 + 0) * 16 + quad * 4 + r) * 66 + nt * 16 + lm];
                float oiv = Oi[nt][r] + Of[((qg * 2 + 1) * 16 + quad * 4 + r) * 66 + nt * 16 + lm];
                size_t o = mbase + (size_t)r * C_DIM + colb + nt * 16;
                ABr[o] = (bf16)(orv * linv[r]);
                ABi[o] = (bf16)(oiv * linv[r]);
            }
    }
}

// ---------------------------------------------------------------------------
extern "C" void kernel_launch(void* const* d_in, const int* in_sizes, int n_in,
                              void* d_out, int out_size, void* d_ws, size_t ws_size,
                              hipStream_t stream) {
    const float* x  = (const float*)d_in[0];
    const float* wq = (const float*)d_in[1];
    const float* bq = (const float*)d_in[2];
    const float* wk = (const float*)d_in[3];
    const float* bk = (const float*)d_in[4];
    const float* wv = (const float*)d_in[5];
    const float* bv = (const float*)d_in[6];
    const float* wo = (const float*)d_in[7];
    const float* bo = (const float*)d_in[8];

    float* rope = (float*)d_ws;                       // 131072 floats (512 KB)
    bf16* w = (bf16*)(rope + 131072);
    const size_t MSZ = (size_t)2048 * 1024;
    const size_t WSZ = (size_t)1024 * 1024;
    const size_t PSZ = (size_t)2 * NH_ * T_SEQ * H_DIM;

    bf16 *Xr = w, *Xi = Xr + MSZ;
    bf16 *Wqr = Xi + MSZ,  *Wqi = Wqr + WSZ;
    bf16 *Wkr = Wqi + WSZ, *Wki = Wkr + WSZ;
    bf16 *Wvr = Wki + WSZ, *Wvi = Wvr + WSZ;
    bf16 *Wor = Wvi + WSZ, *Woi = Wor + WSZ;
    bf16 *Qr = Woi + WSZ, *Qi = Qr + PSZ;
    bf16 *Kr = Qi + PSZ,  *Ki = Kr + PSZ;
    bf16 *Vr = Ki + PSZ,  *Vi = Vr + PSZ;
    bf16 *ABr = Vi + PSZ, *ABi = ABr + MSZ;

    split_all<<<dim3(1024, 6), 256, 0, stream>>>(x, wq, wk, wv, wo,
        Xr, Xi, Wqr, Wqi, Wkr, Wki, Wvr, Wvi, Wor, Woi, rope);

    qkv_gemm<<<dim3(16, 16, 3), 256, 0, stream>>>(
        Xr, Xi, Wqr, Wqi, Wkr, Wki, Wvr, Wvi, bq, bk, bv, rope,
        Qr, Qi, Kr, Ki, Vr, Vi);

    attn_mfma<<<dim3(16, 16, 2), 512, 0, stream>>>(
        Qr, Qi, Kr, Ki, Vr, Vi, ABr, ABi);

    out_gemm<<<dim3(16, 32), 256, 0, stream>>>(ABr, ABi, Wor, Woi, bo, (float*)d_out);
}